// Round 6
// baseline (373.000 us; speedup 1.0000x reference)
//
#include <hip/hip_runtime.h>
#include <math.h>

#define BATCH 64
#define SLATES 25
#define KPS 20
#define EDIM 256
#define DDIM 512
#define HEADS 8
#define HD 64
#define LFULL 501
#define NROWS 500
#define MTOT (BATCH*NROWS)   // 32000
#define CMAX 512             // compacted key capacity
#define NQKV 1536            // packed q|k|v output dim

typedef __attribute__((ext_vector_type(8))) short short8;
typedef __attribute__((ext_vector_type(4))) float f32x4;

__device__ __forceinline__ unsigned short f2bf(float x) {
    unsigned int u = __builtin_bit_cast(unsigned int, x);
    u = (u + 0x7FFFu + ((u >> 16) & 1u)) >> 16;
    return (unsigned short)u;
}
__device__ __forceinline__ float bf2f(unsigned short s) {
    unsigned int u = ((unsigned int)s) << 16;
    return __builtin_bit_cast(float, u);
}
__device__ __forceinline__ float gelu_exact(float x) {
    return 0.5f * x * (1.0f + erff(x * 0.70710678118654752440f));
}
__device__ __forceinline__ void gload16(const void* g, void* l) {
    __builtin_amdgcn_global_load_lds(
        (const __attribute__((address_space(1))) void*)g,
        (__attribute__((address_space(3))) void*)l, 16, 0, 0);
}

// ---------------------------------------------------------------------------
// fp32 -> bf16 converts / weight packing
// ---------------------------------------------------------------------------
__global__ __launch_bounds__(256) void cvt_kernel(
    const float* __restrict__ src, unsigned short* __restrict__ dst, int n4)
{
    const int i = blockIdx.x * 256 + threadIdx.x;
    if (i >= n4) return;
    float4 v = ((const float4*)src)[i];
    ushort4 o;
    o.x = f2bf(v.x); o.y = f2bf(v.y); o.z = f2bf(v.z); o.w = f2bf(v.w);
    ((ushort4*)dst)[i] = o;
}

struct Cvt2 { const float* s[2]; unsigned short* d[2]; };
__global__ __launch_bounds__(256) void cvt2_kernel(Cvt2 a, int n4)
{
    const int i = blockIdx.x * 256 + threadIdx.x;
    if (i >= n4) return;
    const int y = blockIdx.y;
    float4 v = ((const float4*)a.s[y])[i];
    ushort4 o;
    o.x = f2bf(v.x); o.y = f2bf(v.y); o.z = f2bf(v.z); o.w = f2bf(v.w);
    ((ushort4*)a.d[y])[i] = o;
}

// Pack [Wq;Wk;Wv][:, 0:256] -> (1536 x 256) bf16
__global__ __launch_bounds__(256) void packqkv_kernel(
    const float* __restrict__ Wq, const float* __restrict__ Wk,
    const float* __restrict__ Wv, unsigned short* __restrict__ dst)
{
    const int y = blockIdx.y;
    const float* W = (y == 0) ? Wq : (y == 1) ? Wk : Wv;
    const int i = blockIdx.x * 256 + threadIdx.x;   // float4 index over 512x256
    const int row = i >> 6, c4 = (i & 63) * 4;
    float4 v = *(const float4*)&W[(size_t)row * DDIM + c4];
    ushort4 o;
    o.x = f2bf(v.x); o.y = f2bf(v.y); o.z = f2bf(v.z); o.w = f2bf(v.w);
    *(ushort4*)&dst[((size_t)y * DDIM + row) * EDIM + c4] = o;
}

// ---------------------------------------------------------------------------
// Click compaction: one wave per batch.
// ---------------------------------------------------------------------------
__global__ __launch_bounds__(64) void compact_kernel(
    const int* __restrict__ resp, int* __restrict__ cidx, int* __restrict__ cnt)
{
    const int b = blockIdx.x, lane = threadIdx.x;
    int a[8]; int c = 0;
#pragma unroll
    for (int j = 0; j < 8; ++j) {
        const int l = lane * 8 + j;
        int al = 0;
        if (l == 0) al = 1;
        else if (l <= NROWS) al = (resp[(size_t)b * NROWS + l - 1] > 0) ? 1 : 0;
        a[j] = al; c += al;
    }
    int incl = c;
#pragma unroll
    for (int off = 1; off < 64; off <<= 1) {
        int t = __shfl_up(incl, off, 64);
        if (lane >= off) incl += t;
    }
    int run = incl - c;
#pragma unroll
    for (int j = 0; j < 8; ++j) {
        const int l = lane * 8 + j;
        if (l >= 1 && l <= 481 && (l % 20) == 1)
            cnt[b * 32 + (l - 1) / 20] = run;
        cidx[b * 512 + l] = a[j] ? run : -1;
        run += a[j];
    }
}

// ---------------------------------------------------------------------------
// Per-batch user bias tables (packed [B][1536]) + position-0 rows.
// ---------------------------------------------------------------------------
__global__ __launch_bounds__(256) void user_bias_kernel(
    const float* __restrict__ user,
    const float* __restrict__ Wq, const float* __restrict__ bq,
    const float* __restrict__ Wk, const float* __restrict__ bk,
    const float* __restrict__ Wv, const float* __restrict__ bv,
    float* __restrict__ uball,
    unsigned short* __restrict__ qb, unsigned short* __restrict__ kc,
    unsigned short* __restrict__ vc)
{
    const int b = blockIdx.x;
    const int y = blockIdx.y;
    const int tid = threadIdx.x;
    const float* W  = (y == 0) ? Wq : (y == 1) ? Wk : Wv;
    const float* bi = (y == 0) ? bq : (y == 1) ? bk : bv;

    __shared__ float us[EDIM];
    if (tid < EDIM) us[tid] = user[b * EDIM + tid];
    __syncthreads();
    for (int o = tid; o < DDIM; o += 256) {
        float s = bi[o];
        const float* wr = &W[(size_t)o * DDIM + EDIM];
#pragma unroll 4
        for (int e = 0; e < EDIM; ++e) s += us[e] * wr[e];
        uball[(size_t)b * NQKV + y * DDIM + o] = s;
        const int hh = o >> 6, dd = o & 63;
        const size_t bh = (size_t)b * HEADS + hh;
        if (y == 0)      qb[(bh * LFULL) * HD + dd] = f2bf(bi[o]);
        else if (y == 1) kc[(bh * CMAX) * HD + dd] = f2bf(bi[o]);
        else             vc[(bh * HD + dd) * CMAX] = f2bf(bi[o]);
    }
}

// ---------------------------------------------------------------------------
// Merged QKV GEMM, 2-phase double-buffered staging.
// A (32000 x 256) @ Wqkv(1536 x 256)^T + uball. Outputs: q head-major,
// K compacted, V^T compacted.
// ---------------------------------------------------------------------------
__global__ __launch_bounds__(256) void gemm_qkv(
    const unsigned short* __restrict__ A,
    const unsigned short* __restrict__ Wqkv,
    const float* __restrict__ uball, const int* __restrict__ cidx,
    unsigned short* __restrict__ oq, unsigned short* __restrict__ ok,
    unsigned short* __restrict__ ov)
{
    const int tid = threadIdx.x;
    const int n0 = blockIdx.x * 128;   // 0..1535
    const int m0 = blockIdx.y * 128;
    const int lane = tid & 63, wid = tid >> 6;
    const int wm = (wid & 1) * 64, wn = (wid >> 1) * 64;

    __shared__ unsigned short As[2][128][32];
    __shared__ unsigned short Ws[2][128][32];

    f32x4 acc[4][4];
#pragma unroll
    for (int i = 0; i < 4; ++i)
#pragma unroll
        for (int j = 0; j < 4; ++j) acc[i][j] = (f32x4){0.f, 0.f, 0.f, 0.f};

    const unsigned short* gA0 = &A[(size_t)(m0 + wid * 16 + (lane >> 2)) * EDIM + (lane & 3) * 8];
    const unsigned short* gA1 = gA0 + (size_t)64 * EDIM;
    const unsigned short* gW0 = &Wqkv[(size_t)(n0 + wid * 16 + (lane >> 2)) * EDIM + (lane & 3) * 8];
    const unsigned short* gW1 = gW0 + (size_t)64 * EDIM;
    const int frow = lane & 15, fk = (lane >> 4) * 8;

    // prologue stage into buf 0
    gload16(gA0, &As[0][wid * 16][0]);
    gload16(gA1, &As[0][64 + wid * 16][0]);
    gload16(gW0, &Ws[0][wid * 16][0]);
    gload16(gW1, &Ws[0][64 + wid * 16][0]);

    const int nst = EDIM / 32;   // 8
    for (int t = 0; t < nst; ++t) {
        const int cur = t & 1;
        __syncthreads();                       // drains buf[cur] loads
        if (t + 1 < nst) {                     // issue next tile into buf^1
            const int k0 = (t + 1) * 32, nb = cur ^ 1;
            gload16(gA0 + k0, &As[nb][wid * 16][0]);
            gload16(gA1 + k0, &As[nb][64 + wid * 16][0]);
            gload16(gW0 + k0, &Ws[nb][wid * 16][0]);
            gload16(gW1 + k0, &Ws[nb][64 + wid * 16][0]);
        }
        short8 af[4], wf[4];
#pragma unroll
        for (int mi = 0; mi < 4; ++mi)
            af[mi] = *(const short8*)&As[cur][wm + mi * 16 + frow][fk];
#pragma unroll
        for (int ni = 0; ni < 4; ++ni)
            wf[ni] = *(const short8*)&Ws[cur][wn + ni * 16 + frow][fk];
#pragma unroll
        for (int mi = 0; mi < 4; ++mi)
#pragma unroll
            for (int ni = 0; ni < 4; ++ni)
                acc[mi][ni] = __builtin_amdgcn_mfma_f32_16x16x32_bf16(
                    af[mi], wf[ni], acc[mi][ni], 0, 0, 0);
    }

    const int z = n0 >> 9;   // 0=q 1=k 2=v (block fully inside one)
#pragma unroll
    for (int mi = 0; mi < 4; ++mi) {
#pragma unroll
        for (int ni = 0; ni < 4; ++ni) {
            const int np = n0 + wn + ni * 16 + frow;
            const int nn = np & 511, hh = nn >> 6, dd = nn & 63;
#pragma unroll
            for (int r = 0; r < 4; ++r) {
                const int m = m0 + wm + mi * 16 + (lane >> 4) * 4 + r;
                const int b = m / NROWS;
                const int l = m - b * NROWS + 1;
                const size_t bh = (size_t)b * HEADS + hh;
                const float v = acc[mi][ni][r] + uball[(size_t)b * NQKV + np];
                if (z == 0) {
                    oq[(bh * LFULL + l) * HD + dd] = f2bf(v);
                } else {
                    const int c = cidx[b * 512 + l];
                    if (c >= 0) {
                        if (z == 1) ok[(bh * CMAX + c) * HD + dd] = f2bf(v);
                        else        ov[(bh * HD + dd) * CMAX + c] = f2bf(v);
                    }
                }
            }
        }
    }
}

// ---------------------------------------------------------------------------
// Generic bf16 GEMM, 2-phase staging.
// MODE 1: +bias, fp32 out. MODE 2: +bias, gelu, dot with W2 -> 8 partials/row.
// ---------------------------------------------------------------------------
template <int MODE>
__global__ __launch_bounds__(256) void gemm_bf16(
    const unsigned short* __restrict__ A,
    const unsigned short* __restrict__ W,
    const float* __restrict__ bias, void* __restrict__ outp,
    const float* __restrict__ W2, float* __restrict__ part)
{
    const int tid = threadIdx.x;
    const int n0 = blockIdx.x * 128;
    const int m0 = blockIdx.y * 128;
    const int lane = tid & 63, wid = tid >> 6;
    const int wm = (wid & 1) * 64, wn = (wid >> 1) * 64;

    __shared__ unsigned short As[2][128][32];
    __shared__ unsigned short Ws[2][128][32];

    f32x4 acc[4][4];
#pragma unroll
    for (int i = 0; i < 4; ++i)
#pragma unroll
        for (int j = 0; j < 4; ++j) acc[i][j] = (f32x4){0.f, 0.f, 0.f, 0.f};

    const unsigned short* gA0 = &A[(size_t)(m0 + wid * 16 + (lane >> 2)) * DDIM + (lane & 3) * 8];
    const unsigned short* gA1 = gA0 + (size_t)64 * DDIM;
    const unsigned short* gW0 = &W[(size_t)(n0 + wid * 16 + (lane >> 2)) * DDIM + (lane & 3) * 8];
    const unsigned short* gW1 = gW0 + (size_t)64 * DDIM;
    const int frow = lane & 15, fk = (lane >> 4) * 8;

    gload16(gA0, &As[0][wid * 16][0]);
    gload16(gA1, &As[0][64 + wid * 16][0]);
    gload16(gW0, &Ws[0][wid * 16][0]);
    gload16(gW1, &Ws[0][64 + wid * 16][0]);

    const int nst = DDIM / 32;   // 16
    for (int t = 0; t < nst; ++t) {
        const int cur = t & 1;
        __syncthreads();
        if (t + 1 < nst) {
            const int k0 = (t + 1) * 32, nb = cur ^ 1;
            gload16(gA0 + k0, &As[nb][wid * 16][0]);
            gload16(gA1 + k0, &As[nb][64 + wid * 16][0]);
            gload16(gW0 + k0, &Ws[nb][wid * 16][0]);
            gload16(gW1 + k0, &Ws[nb][64 + wid * 16][0]);
        }
        short8 af[4], wf[4];
#pragma unroll
        for (int mi = 0; mi < 4; ++mi)
            af[mi] = *(const short8*)&As[cur][wm + mi * 16 + frow][fk];
#pragma unroll
        for (int ni = 0; ni < 4; ++ni)
            wf[ni] = *(const short8*)&Ws[cur][wn + ni * 16 + frow][fk];
#pragma unroll
        for (int mi = 0; mi < 4; ++mi)
#pragma unroll
            for (int ni = 0; ni < 4; ++ni)
                acc[mi][ni] = __builtin_amdgcn_mfma_f32_16x16x32_bf16(
                    af[mi], wf[ni], acc[mi][ni], 0, 0, 0);
    }

    if (MODE == 1) {
#pragma unroll
        for (int mi = 0; mi < 4; ++mi)
#pragma unroll
            for (int ni = 0; ni < 4; ++ni) {
                const int n = n0 + wn + ni * 16 + frow;
#pragma unroll
                for (int r = 0; r < 4; ++r) {
                    const int m = m0 + wm + mi * 16 + (lane >> 4) * 4 + r;
                    ((float*)outp)[(size_t)m * DDIM + n] = acc[mi][ni][r] + bias[n];
                }
            }
    } else {
        float w2v[4], bv4[4];
#pragma unroll
        for (int ni = 0; ni < 4; ++ni) {
            const int n = n0 + wn + ni * 16 + frow;
            w2v[ni] = W2[n];
            bv4[ni] = bias[n];
        }
        float ps[4][4];
#pragma unroll
        for (int mi = 0; mi < 4; ++mi)
#pragma unroll
            for (int r = 0; r < 4; ++r) ps[mi][r] = 0.f;
#pragma unroll
        for (int mi = 0; mi < 4; ++mi)
#pragma unroll
            for (int ni = 0; ni < 4; ++ni)
#pragma unroll
                for (int r = 0; r < 4; ++r)
                    ps[mi][r] += gelu_exact(acc[mi][ni][r] + bv4[ni]) * w2v[ni];
        const int slot = (n0 >> 7) * 2 + (wn >> 6);
#pragma unroll
        for (int mi = 0; mi < 4; ++mi)
#pragma unroll
            for (int r = 0; r < 4; ++r) {
                float s = ps[mi][r];
                s += __shfl_xor(s, 1, 64);
                s += __shfl_xor(s, 2, 64);
                s += __shfl_xor(s, 4, 64);
                s += __shfl_xor(s, 8, 64);
                if (frow == 0) {
                    const int m = m0 + wm + mi * 16 + (lane >> 4) * 4 + r;
                    part[(size_t)m * 8 + slot] = s;
                }
            }
    }
}

// ---------------------------------------------------------------------------
// Final reduction: out[m] = b2 + sum of 8 partials.
// ---------------------------------------------------------------------------
__global__ __launch_bounds__(256) void w2red_kernel(
    const float* __restrict__ part, const float* __restrict__ b2,
    float* __restrict__ out)
{
    const int m = blockIdx.x * 256 + threadIdx.x;
    if (m >= MTOT) return;
    const float* p = part + (size_t)m * 8;
    float s = b2[0];
#pragma unroll
    for (int i = 0; i < 8; ++i) s += p[i];
    out[m] = s;
}

// ---------------------------------------------------------------------------
// Attention (unchanged from R5): compacted keys, bf16 score LDS,
// barrier-free MFMA loops.
// ---------------------------------------------------------------------------
__global__ __launch_bounds__(256) void attn_mfma(
    const unsigned short* __restrict__ qx, const unsigned short* __restrict__ kc,
    const unsigned short* __restrict__ vc, const int* __restrict__ cnt,
    unsigned short* __restrict__ outb)
{
    const int s0 = blockIdx.x, h = blockIdx.y, b = blockIdx.z;
    const int tid = threadIdx.x, lane = tid & 63, w = tid >> 6;
    const int nck = cnt[b * 32 + s0];
    const int NT = (nck + 63) >> 6;
    const int NK = NT << 6;

    __shared__ __align__(16) unsigned short scb[KPS][520];
    __shared__ float invb[KPS];

    const int frow = lane & 15, fk = (lane >> 4) * 8;
    const size_t bh = (size_t)b * HEADS + h;
    const unsigned short* kbase = kc + bh * (CMAX * HD);
    const unsigned short* vbase = vc + bh * (HD * CMAX);

    short8 qf[2][2];
#pragma unroll
    for (int mi = 0; mi < 2; ++mi) {
        const int qrow = mi * 16 + frow;
#pragma unroll
        for (int ks = 0; ks < 2; ++ks) {
            short8 v = {};
            if (qrow < KPS)
                v = *(const short8*)&qx[(bh * LFULL + s0 * KPS + 1 + qrow) * HD
                                        + ks * 32 + fk];
            qf[mi][ks] = v;
        }
    }

    for (int t = 0; t < NT; ++t) {
        const int key = (t << 6) + w * 16 + frow;
        const unsigned short* kr = kbase + (size_t)key * HD;
        const short8 kf0 = *(const short8*)(kr + fk);
        const short8 kf1 = *(const short8*)(kr + 32 + fk);
        f32x4 s2[2];
#pragma unroll
        for (int mi = 0; mi < 2; ++mi) {
            s2[mi] = (f32x4){0.f, 0.f, 0.f, 0.f};
            s2[mi] = __builtin_amdgcn_mfma_f32_16x16x32_bf16(qf[mi][0], kf0, s2[mi], 0, 0, 0);
            s2[mi] = __builtin_amdgcn_mfma_f32_16x16x32_bf16(qf[mi][1], kf1, s2[mi], 0, 0, 0);
        }
        const bool allow = key < nck;
#pragma unroll
        for (int mi = 0; mi < 2; ++mi)
#pragma unroll
            for (int r = 0; r < 4; ++r) {
                const int row = mi * 16 + (lane >> 4) * 4 + r;
                if (row < KPS)
                    scb[row][key] = f2bf(allow ? s2[mi][r] * 0.125f : -1e30f);
            }
    }
    __syncthreads();

    for (int r = w; r < KPS; r += 4) {
        float xv[8];
        float mx = -1e30f;
#pragma unroll
        for (int i = 0; i < 8; ++i) {
            const int k_ = lane + i * 64;
            if (k_ < NK) { xv[i] = bf2f(scb[r][k_]); mx = fmaxf(mx, xv[i]); }
        }
#pragma unroll
        for (int off = 32; off; off >>= 1) mx = fmaxf(mx, __shfl_xor(mx, off, 64));
        float ss = 0.f;
#pragma unroll
        for (int i = 0; i < 8; ++i) {
            const int k_ = lane + i * 64;
            if (k_ < NK) {
                const float p = __expf(xv[i] - mx);
                ss += p;
                scb[r][k_] = f2bf(p);
            }
        }
#pragma unroll
        for (int off = 32; off; off >>= 1) ss += __shfl_xor(ss, off, 64);
        if (lane == 0) invb[r] = 1.0f / ss;
    }
    __syncthreads();

    f32x4 po[2];
    po[0] = (f32x4){0.f, 0.f, 0.f, 0.f};
    po[1] = (f32x4){0.f, 0.f, 0.f, 0.f};
    const unsigned short* vrow = vbase + (size_t)(w * 16 + frow) * CMAX;
    for (int t = 0; t < NT; ++t) {
#pragma unroll
        for (int ks = 0; ks < 2; ++ks) {
            const int kb0 = (t << 6) + ks * 32 + fk;
            short8 vf;
            if (t + 1 < NT) {
                vf = *(const short8*)(vrow + kb0);
            } else if (kb0 + 8 <= nck) {
                vf = *(const short8*)(vrow + kb0);
            } else {
#pragma unroll
                for (int j = 0; j < 8; ++j)
                    vf[j] = (kb0 + j < nck) ? (short)vrow[kb0 + j] : (short)0;
            }
#pragma unroll
            for (int mi = 0; mi < 2; ++mi) {
                short8 pf = {};
                const int prow = mi * 16 + frow;
                if (prow < KPS)
                    pf = *(const short8*)&scb[prow][kb0];
                po[mi] = __builtin_amdgcn_mfma_f32_16x16x32_bf16(pf, vf, po[mi], 0, 0, 0);
            }
        }
    }

#pragma unroll
    for (int mi = 0; mi < 2; ++mi)
#pragma unroll
        for (int r = 0; r < 4; ++r) {
            const int row = mi * 16 + (lane >> 4) * 4 + r;
            if (row < KPS)
                outb[((size_t)b * NROWS + s0 * KPS + row) * DDIM
                     + h * HD + w * 16 + frow] = f2bf(po[mi][r] * invb[row]);
        }
}

// ---------------------------------------------------------------------------
// LayerNorm fp32 -> bf16.
// ---------------------------------------------------------------------------
__global__ __launch_bounds__(256) void ln_kernel(
    const float* __restrict__ f, const float* __restrict__ g,
    const float* __restrict__ bt, unsigned short* __restrict__ o)
{
    const int row = blockIdx.x * 4 + (threadIdx.x >> 6);
    const int lane = threadIdx.x & 63;
    const float* fr = f + (size_t)row * DDIM;
    float xv[8];
    float s = 0.f;
#pragma unroll
    for (int i = 0; i < 8; ++i) { xv[i] = fr[lane + i * 64]; s += xv[i]; }
#pragma unroll
    for (int off = 32; off; off >>= 1) s += __shfl_xor(s, off, 64);
    const float mu = s * (1.0f / DDIM);
    float var = 0.f;
#pragma unroll
    for (int i = 0; i < 8; ++i) { const float d0 = xv[i] - mu; var += d0 * d0; }
#pragma unroll
    for (int off = 32; off; off >>= 1) var += __shfl_xor(var, off, 64);
    const float rs = rsqrtf(var * (1.0f / DDIM) + 1e-5f);
#pragma unroll
    for (int i = 0; i < 8; ++i) {
        const int d0 = lane + i * 64;
        o[(size_t)row * DDIM + d0] = f2bf((xv[i] - mu) * rs * g[d0] + bt[d0]);
    }
}

// ---------------------------------------------------------------------------
extern "C" void kernel_launch(void* const* d_in, const int* in_sizes, int n_in,
                              void* d_out, int out_size, void* d_ws, size_t ws_size,
                              hipStream_t stream)
{
    const float* item = (const float*)d_in[0];
    const float* user = (const float*)d_in[1];
    const int*   resp = (const int*)d_in[2];
    const float* Wq = (const float*)d_in[3];  const float* bq = (const float*)d_in[4];
    const float* Wk = (const float*)d_in[5];  const float* bk = (const float*)d_in[6];
    const float* Wv = (const float*)d_in[7];  const float* bv = (const float*)d_in[8];
    const float* Wo = (const float*)d_in[9];  const float* bo = (const float*)d_in[10];
    const float* lng = (const float*)d_in[11]; const float* lnb = (const float*)d_in[12];
    const float* W1 = (const float*)d_in[13]; const float* b1 = (const float*)d_in[14];
    const float* W2 = (const float*)d_in[15]; const float* b2 = (const float*)d_in[16];
    float* out = (float*)d_out;

    char* p = (char*)d_ws;
    auto alloc = [&](size_t bytes) { char* r = p; p += (bytes + 255) & ~(size_t)255; return r; };
    const size_t NITEM = (size_t)BATCH * NROWS * EDIM;
    const size_t NW    = (size_t)DDIM * DDIM;
    const size_t NQ    = (size_t)BATCH * HEADS * LFULL * HD;
    const size_t NC    = (size_t)BATCH * HEADS * CMAX * HD;
    const size_t NMD   = (size_t)MTOT * DDIM;
    const size_t PAD   = 8192;

    unsigned short* itemb  = (unsigned short*)alloc(NITEM * 2);
    unsigned short* Wqkvb  = (unsigned short*)alloc((size_t)NQKV * EDIM * 2);
    unsigned short* Wob    = (unsigned short*)alloc(NW * 2);
    unsigned short* W1b    = (unsigned short*)alloc(NW * 2);
    unsigned short* qb     = (unsigned short*)alloc(NQ * 2 + PAD);
    unsigned short* kcb    = (unsigned short*)alloc(NC * 2 + PAD);
    unsigned short* vcb    = (unsigned short*)alloc(NC * 2 + PAD);
    unsigned short* aob    = (unsigned short*)alloc(NMD * 2);
    float* fbuf  = (float*)alloc(NMD * 4);
    float* uball = (float*)alloc((size_t)BATCH * NQKV * 4);
    float* part  = (float*)alloc((size_t)MTOT * 8 * 4);
    int* cidx    = (int*)alloc((size_t)BATCH * 512 * 4);
    int* cnt     = (int*)alloc((size_t)BATCH * 32 * 4);

    cvt_kernel<<<dim3((NITEM / 4 + 255) / 256), 256, 0, stream>>>(item, itemb, NITEM / 4);
    packqkv_kernel<<<dim3(DDIM * EDIM / 4 / 256, 3), 256, 0, stream>>>(Wq, Wk, Wv, Wqkvb);
    Cvt2 c2;
    c2.s[0] = Wo; c2.s[1] = W1; c2.d[0] = Wob; c2.d[1] = W1b;
    cvt2_kernel<<<dim3(NW / 4 / 256, 2), 256, 0, stream>>>(c2, NW / 4);

    compact_kernel<<<dim3(BATCH), 64, 0, stream>>>(resp, cidx, cnt);

    user_bias_kernel<<<dim3(BATCH, 3), 256, 0, stream>>>(
        user, Wq, bq, Wk, bk, Wv, bv, uball, qb, kcb, vcb);

    gemm_qkv<<<dim3(NQKV / 128, MTOT / 128), 256, 0, stream>>>(
        itemb, Wqkvb, uball, cidx, qb, kcb, vcb);

    attn_mfma<<<dim3(SLATES, HEADS, BATCH), 256, 0, stream>>>(qb, kcb, vcb, cnt, aob);

    dim3 gg(DDIM / 128, MTOT / 128);
    gemm_bf16<1><<<gg, 256, 0, stream>>>(aob, Wob, bo, fbuf, nullptr, nullptr);
    ln_kernel<<<dim3(MTOT / 4), 256, 0, stream>>>(fbuf, lng, lnb, aob);
    gemm_bf16<2><<<gg, 256, 0, stream>>>(aob, W1b, b1, nullptr, W2, part);
    w2red_kernel<<<dim3((MTOT + 255) / 256), 256, 0, stream>>>(part, b2, out);
}

// Round 7
// 351.685 us; speedup vs baseline: 1.0606x; 1.0606x over previous
//
#include <hip/hip_runtime.h>
#include <math.h>

#define BATCH 64
#define SLATES 25
#define KPS 20
#define EDIM 256
#define DDIM 512
#define HEADS 8
#define HD 64
#define LFULL 501
#define NROWS 500
#define MTOT (BATCH*NROWS)   // 32000
#define CMAX 512             // compacted key capacity
#define NQKV 1536            // packed q|k|v output dim

typedef __attribute__((ext_vector_type(8))) short short8;
typedef __attribute__((ext_vector_type(4))) float f32x4;

__device__ __forceinline__ unsigned short f2bf(float x) {
    unsigned int u = __builtin_bit_cast(unsigned int, x);
    u = (u + 0x7FFFu + ((u >> 16) & 1u)) >> 16;
    return (unsigned short)u;
}
__device__ __forceinline__ float bf2f(unsigned short s) {
    unsigned int u = ((unsigned int)s) << 16;
    return __builtin_bit_cast(float, u);
}
__device__ __forceinline__ float gelu_exact(float x) {
    return 0.5f * x * (1.0f + erff(x * 0.70710678118654752440f));
}
__device__ __forceinline__ void gload16(const void* g, void* l) {
    __builtin_amdgcn_global_load_lds(
        (const __attribute__((address_space(1))) void*)g,
        (__attribute__((address_space(3))) void*)l, 16, 0, 0);
}

// ---------------------------------------------------------------------------
// fp32 -> bf16 converts / weight packing
// ---------------------------------------------------------------------------
__global__ __launch_bounds__(256) void cvt_kernel(
    const float* __restrict__ src, unsigned short* __restrict__ dst, int n4)
{
    const int i = blockIdx.x * 256 + threadIdx.x;
    if (i >= n4) return;
    float4 v = ((const float4*)src)[i];
    ushort4 o;
    o.x = f2bf(v.x); o.y = f2bf(v.y); o.z = f2bf(v.z); o.w = f2bf(v.w);
    ((ushort4*)dst)[i] = o;
}

struct Cvt2 { const float* s[2]; unsigned short* d[2]; };
__global__ __launch_bounds__(256) void cvt2_kernel(Cvt2 a, int n4)
{
    const int i = blockIdx.x * 256 + threadIdx.x;
    if (i >= n4) return;
    const int y = blockIdx.y;
    float4 v = ((const float4*)a.s[y])[i];
    ushort4 o;
    o.x = f2bf(v.x); o.y = f2bf(v.y); o.z = f2bf(v.z); o.w = f2bf(v.w);
    ((ushort4*)a.d[y])[i] = o;
}

// Pack [Wq;Wk;Wv][:, 0:256] -> (1536 x 256) bf16
__global__ __launch_bounds__(256) void packqkv_kernel(
    const float* __restrict__ Wq, const float* __restrict__ Wk,
    const float* __restrict__ Wv, unsigned short* __restrict__ dst)
{
    const int y = blockIdx.y;
    const float* W = (y == 0) ? Wq : (y == 1) ? Wk : Wv;
    const int i = blockIdx.x * 256 + threadIdx.x;
    const int row = i >> 6, c4 = (i & 63) * 4;
    float4 v = *(const float4*)&W[(size_t)row * DDIM + c4];
    ushort4 o;
    o.x = f2bf(v.x); o.y = f2bf(v.y); o.z = f2bf(v.z); o.w = f2bf(v.w);
    *(ushort4*)&dst[((size_t)y * DDIM + row) * EDIM + c4] = o;
}

// ---------------------------------------------------------------------------
// Click compaction: one wave per batch.
// ---------------------------------------------------------------------------
__global__ __launch_bounds__(64) void compact_kernel(
    const int* __restrict__ resp, int* __restrict__ cidx, int* __restrict__ cnt)
{
    const int b = blockIdx.x, lane = threadIdx.x;
    int a[8]; int c = 0;
#pragma unroll
    for (int j = 0; j < 8; ++j) {
        const int l = lane * 8 + j;
        int al = 0;
        if (l == 0) al = 1;
        else if (l <= NROWS) al = (resp[(size_t)b * NROWS + l - 1] > 0) ? 1 : 0;
        a[j] = al; c += al;
    }
    int incl = c;
#pragma unroll
    for (int off = 1; off < 64; off <<= 1) {
        int t = __shfl_up(incl, off, 64);
        if (lane >= off) incl += t;
    }
    int run = incl - c;
#pragma unroll
    for (int j = 0; j < 8; ++j) {
        const int l = lane * 8 + j;
        if (l >= 1 && l <= 481 && (l % 20) == 1)
            cnt[b * 32 + (l - 1) / 20] = run;
        cidx[b * 512 + l] = a[j] ? run : -1;
        run += a[j];
    }
}

// ---------------------------------------------------------------------------
// Per-batch user bias tables (packed [B][1536]) + position-0 rows.
// ---------------------------------------------------------------------------
__global__ __launch_bounds__(256) void user_bias_kernel(
    const float* __restrict__ user,
    const float* __restrict__ Wq, const float* __restrict__ bq,
    const float* __restrict__ Wk, const float* __restrict__ bk,
    const float* __restrict__ Wv, const float* __restrict__ bv,
    float* __restrict__ uball,
    unsigned short* __restrict__ qb, unsigned short* __restrict__ kc,
    unsigned short* __restrict__ vc)
{
    const int b = blockIdx.x;
    const int y = blockIdx.y;
    const int tid = threadIdx.x;
    const float* W  = (y == 0) ? Wq : (y == 1) ? Wk : Wv;
    const float* bi = (y == 0) ? bq : (y == 1) ? bk : bv;

    __shared__ float us[EDIM];
    if (tid < EDIM) us[tid] = user[b * EDIM + tid];
    __syncthreads();
    for (int o = tid; o < DDIM; o += 256) {
        float s = bi[o];
        const float* wr = &W[(size_t)o * DDIM + EDIM];
#pragma unroll 4
        for (int e = 0; e < EDIM; ++e) s += us[e] * wr[e];
        uball[(size_t)b * NQKV + y * DDIM + o] = s;
        const int hh = o >> 6, dd = o & 63;
        const size_t bh = (size_t)b * HEADS + hh;
        if (y == 0)      qb[(bh * LFULL) * HD + dd] = f2bf(bi[o]);
        else if (y == 1) kc[(bh * CMAX) * HD + dd] = f2bf(bi[o]);
        else             vc[(bh * HD + dd) * CMAX] = f2bf(bi[o]);
    }
}

// ---------------------------------------------------------------------------
// Merged QKV GEMM with 3-buffer counted-vmcnt pipeline (T3+T4).
// A (32000 x 256) @ Wqkv(1536 x 256)^T + uball.
// ---------------------------------------------------------------------------
__global__ __launch_bounds__(256) void gemm_qkv(
    const unsigned short* __restrict__ A,
    const unsigned short* __restrict__ Wqkv,
    const float* __restrict__ uball, const int* __restrict__ cidx,
    unsigned short* __restrict__ oq, unsigned short* __restrict__ ok,
    unsigned short* __restrict__ ov)
{
    const int tid = threadIdx.x;
    const int n0 = blockIdx.x * 128;   // 0..1535
    const int m0 = blockIdx.y * 128;
    const int lane = tid & 63, wid = tid >> 6;
    const int wm = (wid & 1) * 64, wn = (wid >> 1) * 64;

    __shared__ unsigned short As[3][128][32];
    __shared__ unsigned short Ws[3][128][32];

    f32x4 acc[4][4];
#pragma unroll
    for (int i = 0; i < 4; ++i)
#pragma unroll
        for (int j = 0; j < 4; ++j) acc[i][j] = (f32x4){0.f, 0.f, 0.f, 0.f};

    const unsigned short* gA0 = &A[(size_t)(m0 + wid * 16 + (lane >> 2)) * EDIM + (lane & 3) * 8];
    const unsigned short* gA1 = gA0 + (size_t)64 * EDIM;
    const unsigned short* gW0 = &Wqkv[(size_t)(n0 + wid * 16 + (lane >> 2)) * EDIM + (lane & 3) * 8];
    const unsigned short* gW1 = gW0 + (size_t)64 * EDIM;
    const int frow = lane & 15, fk = (lane >> 4) * 8;

    auto stage = [&](int buf, int k0) {
        gload16(gA0 + k0, &As[buf][wid * 16][0]);
        gload16(gA1 + k0, &As[buf][64 + wid * 16][0]);
        gload16(gW0 + k0, &Ws[buf][wid * 16][0]);
        gload16(gW1 + k0, &Ws[buf][64 + wid * 16][0]);
    };
    stage(0, 0);
    stage(1, 32);

    const int nst = EDIM / 32;   // 8
    for (int t = 0; t < nst; ++t) {
        const int cur = t % 3;
        if (t < nst - 1) asm volatile("s_waitcnt vmcnt(4)" ::: "memory");
        else             asm volatile("s_waitcnt vmcnt(0)" ::: "memory");
        __builtin_amdgcn_s_barrier();
        __builtin_amdgcn_sched_barrier(0);
        short8 af[4], wf[4];
#pragma unroll
        for (int mi = 0; mi < 4; ++mi)
            af[mi] = *(const short8*)&As[cur][wm + mi * 16 + frow][fk];
#pragma unroll
        for (int ni = 0; ni < 4; ++ni)
            wf[ni] = *(const short8*)&Ws[cur][wn + ni * 16 + frow][fk];
#pragma unroll
        for (int mi = 0; mi < 4; ++mi)
#pragma unroll
            for (int ni = 0; ni < 4; ++ni)
                acc[mi][ni] = __builtin_amdgcn_mfma_f32_16x16x32_bf16(
                    af[mi], wf[ni], acc[mi][ni], 0, 0, 0);
        if (t + 2 < nst) stage((t + 2) % 3, (t + 2) * 32);
    }

    const int z = n0 >> 9;   // 0=q 1=k 2=v
#pragma unroll
    for (int mi = 0; mi < 4; ++mi) {
#pragma unroll
        for (int ni = 0; ni < 4; ++ni) {
            const int np = n0 + wn + ni * 16 + frow;
            const int nn = np & 511, hh = nn >> 6, dd = nn & 63;
#pragma unroll
            for (int r = 0; r < 4; ++r) {
                const int m = m0 + wm + mi * 16 + (lane >> 4) * 4 + r;
                const int b = m / NROWS;
                const int l = m - b * NROWS + 1;
                const size_t bh = (size_t)b * HEADS + hh;
                const float v = acc[mi][ni][r] + uball[(size_t)b * NQKV + np];
                if (z == 0) {
                    oq[(bh * LFULL + l) * HD + dd] = f2bf(v);
                } else {
                    const int c = cidx[b * 512 + l];
                    if (c >= 0) {
                        if (z == 1) ok[(bh * CMAX + c) * HD + dd] = f2bf(v);
                        else        ov[(bh * HD + dd) * CMAX + c] = f2bf(v);
                    }
                }
            }
        }
    }
}

// ---------------------------------------------------------------------------
// Generic bf16 GEMM with 3-buffer counted-vmcnt pipeline.
// MODE 1: +bias, fp32 out. MODE 2: +bias, gelu, dot with W2 -> 8 partials/row.
// ---------------------------------------------------------------------------
template <int MODE>
__global__ __launch_bounds__(256) void gemm_bf16(
    const unsigned short* __restrict__ A,
    const unsigned short* __restrict__ W,
    const float* __restrict__ bias, void* __restrict__ outp,
    const float* __restrict__ W2, float* __restrict__ part)
{
    const int tid = threadIdx.x;
    const int n0 = blockIdx.x * 128;
    const int m0 = blockIdx.y * 128;
    const int lane = tid & 63, wid = tid >> 6;
    const int wm = (wid & 1) * 64, wn = (wid >> 1) * 64;

    __shared__ unsigned short As[3][128][32];
    __shared__ unsigned short Ws[3][128][32];

    f32x4 acc[4][4];
#pragma unroll
    for (int i = 0; i < 4; ++i)
#pragma unroll
        for (int j = 0; j < 4; ++j) acc[i][j] = (f32x4){0.f, 0.f, 0.f, 0.f};

    const unsigned short* gA0 = &A[(size_t)(m0 + wid * 16 + (lane >> 2)) * DDIM + (lane & 3) * 8];
    const unsigned short* gA1 = gA0 + (size_t)64 * DDIM;
    const unsigned short* gW0 = &W[(size_t)(n0 + wid * 16 + (lane >> 2)) * DDIM + (lane & 3) * 8];
    const unsigned short* gW1 = gW0 + (size_t)64 * DDIM;
    const int frow = lane & 15, fk = (lane >> 4) * 8;

    auto stage = [&](int buf, int k0) {
        gload16(gA0 + k0, &As[buf][wid * 16][0]);
        gload16(gA1 + k0, &As[buf][64 + wid * 16][0]);
        gload16(gW0 + k0, &Ws[buf][wid * 16][0]);
        gload16(gW1 + k0, &Ws[buf][64 + wid * 16][0]);
    };
    stage(0, 0);
    stage(1, 32);

    const int nst = DDIM / 32;   // 16
    for (int t = 0; t < nst; ++t) {
        const int cur = t % 3;
        if (t < nst - 1) asm volatile("s_waitcnt vmcnt(4)" ::: "memory");
        else             asm volatile("s_waitcnt vmcnt(0)" ::: "memory");
        __builtin_amdgcn_s_barrier();
        __builtin_amdgcn_sched_barrier(0);
        short8 af[4], wf[4];
#pragma unroll
        for (int mi = 0; mi < 4; ++mi)
            af[mi] = *(const short8*)&As[cur][wm + mi * 16 + frow][fk];
#pragma unroll
        for (int ni = 0; ni < 4; ++ni)
            wf[ni] = *(const short8*)&Ws[cur][wn + ni * 16 + frow][fk];
#pragma unroll
        for (int mi = 0; mi < 4; ++mi)
#pragma unroll
            for (int ni = 0; ni < 4; ++ni)
                acc[mi][ni] = __builtin_amdgcn_mfma_f32_16x16x32_bf16(
                    af[mi], wf[ni], acc[mi][ni], 0, 0, 0);
        if (t + 2 < nst) stage((t + 2) % 3, (t + 2) * 32);
    }

    if (MODE == 1) {
#pragma unroll
        for (int mi = 0; mi < 4; ++mi)
#pragma unroll
            for (int ni = 0; ni < 4; ++ni) {
                const int n = n0 + wn + ni * 16 + frow;
#pragma unroll
                for (int r = 0; r < 4; ++r) {
                    const int m = m0 + wm + mi * 16 + (lane >> 4) * 4 + r;
                    ((float*)outp)[(size_t)m * DDIM + n] = acc[mi][ni][r] + bias[n];
                }
            }
    } else {
        float w2v[4], bv4[4];
#pragma unroll
        for (int ni = 0; ni < 4; ++ni) {
            const int n = n0 + wn + ni * 16 + frow;
            w2v[ni] = W2[n];
            bv4[ni] = bias[n];
        }
        float ps[4][4];
#pragma unroll
        for (int mi = 0; mi < 4; ++mi)
#pragma unroll
            for (int r = 0; r < 4; ++r) ps[mi][r] = 0.f;
#pragma unroll
        for (int mi = 0; mi < 4; ++mi)
#pragma unroll
            for (int ni = 0; ni < 4; ++ni)
#pragma unroll
                for (int r = 0; r < 4; ++r)
                    ps[mi][r] += gelu_exact(acc[mi][ni][r] + bv4[ni]) * w2v[ni];
        const int slot = (n0 >> 7) * 2 + (wn >> 6);
#pragma unroll
        for (int mi = 0; mi < 4; ++mi)
#pragma unroll
            for (int r = 0; r < 4; ++r) {
                float s = ps[mi][r];
                s += __shfl_xor(s, 1, 64);
                s += __shfl_xor(s, 2, 64);
                s += __shfl_xor(s, 4, 64);
                s += __shfl_xor(s, 8, 64);
                if (frow == 0) {
                    const int m = m0 + wm + mi * 16 + (lane >> 4) * 4 + r;
                    part[(size_t)m * 8 + slot] = s;
                }
            }
    }
}

// ---------------------------------------------------------------------------
// Final reduction: out[m] = b2 + sum of 8 partials.
// ---------------------------------------------------------------------------
__global__ __launch_bounds__(256) void w2red_kernel(
    const float* __restrict__ part, const float* __restrict__ b2,
    float* __restrict__ out)
{
    const int m = blockIdx.x * 256 + threadIdx.x;
    if (m >= MTOT) return;
    const float* p = part + (size_t)m * 8;
    float s = b2[0];
#pragma unroll
    for (int i = 0; i < 8; ++i) s += p[i];
    out[m] = s;
}

// ---------------------------------------------------------------------------
// Attention (unchanged): compacted keys, bf16 score LDS, barrier-free loops.
// ---------------------------------------------------------------------------
__global__ __launch_bounds__(256) void attn_mfma(
    const unsigned short* __restrict__ qx, const unsigned short* __restrict__ kc,
    const unsigned short* __restrict__ vc, const int* __restrict__ cnt,
    unsigned short* __restrict__ outb)
{
    const int s0 = blockIdx.x, h = blockIdx.y, b = blockIdx.z;
    const int tid = threadIdx.x, lane = tid & 63, w = tid >> 6;
    const int nck = cnt[b * 32 + s0];
    const int NT = (nck + 63) >> 6;
    const int NK = NT << 6;

    __shared__ __align__(16) unsigned short scb[KPS][520];
    __shared__ float invb[KPS];

    const int frow = lane & 15, fk = (lane >> 4) * 8;
    const size_t bh = (size_t)b * HEADS + h;
    const unsigned short* kbase = kc + bh * (CMAX * HD);
    const unsigned short* vbase = vc + bh * (HD * CMAX);

    short8 qf[2][2];
#pragma unroll
    for (int mi = 0; mi < 2; ++mi) {
        const int qrow = mi * 16 + frow;
#pragma unroll
        for (int ks = 0; ks < 2; ++ks) {
            short8 v = {};
            if (qrow < KPS)
                v = *(const short8*)&qx[(bh * LFULL + s0 * KPS + 1 + qrow) * HD
                                        + ks * 32 + fk];
            qf[mi][ks] = v;
        }
    }

    for (int t = 0; t < NT; ++t) {
        const int key = (t << 6) + w * 16 + frow;
        const unsigned short* kr = kbase + (size_t)key * HD;
        const short8 kf0 = *(const short8*)(kr + fk);
        const short8 kf1 = *(const short8*)(kr + 32 + fk);
        f32x4 s2[2];
#pragma unroll
        for (int mi = 0; mi < 2; ++mi) {
            s2[mi] = (f32x4){0.f, 0.f, 0.f, 0.f};
            s2[mi] = __builtin_amdgcn_mfma_f32_16x16x32_bf16(qf[mi][0], kf0, s2[mi], 0, 0, 0);
            s2[mi] = __builtin_amdgcn_mfma_f32_16x16x32_bf16(qf[mi][1], kf1, s2[mi], 0, 0, 0);
        }
        const bool allow = key < nck;
#pragma unroll
        for (int mi = 0; mi < 2; ++mi)
#pragma unroll
            for (int r = 0; r < 4; ++r) {
                const int row = mi * 16 + (lane >> 4) * 4 + r;
                if (row < KPS)
                    scb[row][key] = f2bf(allow ? s2[mi][r] * 0.125f : -1e30f);
            }
    }
    __syncthreads();

    for (int r = w; r < KPS; r += 4) {
        float xv[8];
        float mx = -1e30f;
#pragma unroll
        for (int i = 0; i < 8; ++i) {
            const int k_ = lane + i * 64;
            if (k_ < NK) { xv[i] = bf2f(scb[r][k_]); mx = fmaxf(mx, xv[i]); }
        }
#pragma unroll
        for (int off = 32; off; off >>= 1) mx = fmaxf(mx, __shfl_xor(mx, off, 64));
        float ss = 0.f;
#pragma unroll
        for (int i = 0; i < 8; ++i) {
            const int k_ = lane + i * 64;
            if (k_ < NK) {
                const float p = __expf(xv[i] - mx);
                ss += p;
                scb[r][k_] = f2bf(p);
            }
        }
#pragma unroll
        for (int off = 32; off; off >>= 1) ss += __shfl_xor(ss, off, 64);
        if (lane == 0) invb[r] = 1.0f / ss;
    }
    __syncthreads();

    f32x4 po[2];
    po[0] = (f32x4){0.f, 0.f, 0.f, 0.f};
    po[1] = (f32x4){0.f, 0.f, 0.f, 0.f};
    const unsigned short* vrow = vbase + (size_t)(w * 16 + frow) * CMAX;
    for (int t = 0; t < NT; ++t) {
#pragma unroll
        for (int ks = 0; ks < 2; ++ks) {
            const int kb0 = (t << 6) + ks * 32 + fk;
            short8 vf;
            if (t + 1 < NT) {
                vf = *(const short8*)(vrow + kb0);
            } else if (kb0 + 8 <= nck) {
                vf = *(const short8*)(vrow + kb0);
            } else {
#pragma unroll
                for (int j = 0; j < 8; ++j)
                    vf[j] = (kb0 + j < nck) ? (short)vrow[kb0 + j] : (short)0;
            }
#pragma unroll
            for (int mi = 0; mi < 2; ++mi) {
                short8 pf = {};
                const int prow = mi * 16 + frow;
                if (prow < KPS)
                    pf = *(const short8*)&scb[prow][kb0];
                po[mi] = __builtin_amdgcn_mfma_f32_16x16x32_bf16(pf, vf, po[mi], 0, 0, 0);
            }
        }
    }

#pragma unroll
    for (int mi = 0; mi < 2; ++mi)
#pragma unroll
        for (int r = 0; r < 4; ++r) {
            const int row = mi * 16 + (lane >> 4) * 4 + r;
            if (row < KPS)
                outb[((size_t)b * NROWS + s0 * KPS + row) * DDIM
                     + h * HD + w * 16 + frow] = f2bf(po[mi][r] * invb[row]);
        }
}

// ---------------------------------------------------------------------------
// LayerNorm fp32 -> bf16.
// ---------------------------------------------------------------------------
__global__ __launch_bounds__(256) void ln_kernel(
    const float* __restrict__ f, const float* __restrict__ g,
    const float* __restrict__ bt, unsigned short* __restrict__ o)
{
    const int row = blockIdx.x * 4 + (threadIdx.x >> 6);
    const int lane = threadIdx.x & 63;
    const float* fr = f + (size_t)row * DDIM;
    float xv[8];
    float s = 0.f;
#pragma unroll
    for (int i = 0; i < 8; ++i) { xv[i] = fr[lane + i * 64]; s += xv[i]; }
#pragma unroll
    for (int off = 32; off; off >>= 1) s += __shfl_xor(s, off, 64);
    const float mu = s * (1.0f / DDIM);
    float var = 0.f;
#pragma unroll
    for (int i = 0; i < 8; ++i) { const float d0 = xv[i] - mu; var += d0 * d0; }
#pragma unroll
    for (int off = 32; off; off >>= 1) var += __shfl_xor(var, off, 64);
    const float rs = rsqrtf(var * (1.0f / DDIM) + 1e-5f);
#pragma unroll
    for (int i = 0; i < 8; ++i) {
        const int d0 = lane + i * 64;
        o[(size_t)row * DDIM + d0] = f2bf((xv[i] - mu) * rs * g[d0] + bt[d0]);
    }
}

// ---------------------------------------------------------------------------
extern "C" void kernel_launch(void* const* d_in, const int* in_sizes, int n_in,
                              void* d_out, int out_size, void* d_ws, size_t ws_size,
                              hipStream_t stream)
{
    const float* item = (const float*)d_in[0];
    const float* user = (const float*)d_in[1];
    const int*   resp = (const int*)d_in[2];
    const float* Wq = (const float*)d_in[3];  const float* bq = (const float*)d_in[4];
    const float* Wk = (const float*)d_in[5];  const float* bk = (const float*)d_in[6];
    const float* Wv = (const float*)d_in[7];  const float* bv = (const float*)d_in[8];
    const float* Wo = (const float*)d_in[9];  const float* bo = (const float*)d_in[10];
    const float* lng = (const float*)d_in[11]; const float* lnb = (const float*)d_in[12];
    const float* W1 = (const float*)d_in[13]; const float* b1 = (const float*)d_in[14];
    const float* W2 = (const float*)d_in[15]; const float* b2 = (const float*)d_in[16];
    float* out = (float*)d_out;

    char* p = (char*)d_ws;
    auto alloc = [&](size_t bytes) { char* r = p; p += (bytes + 255) & ~(size_t)255; return r; };
    const size_t NITEM = (size_t)BATCH * NROWS * EDIM;
    const size_t NW    = (size_t)DDIM * DDIM;
    const size_t NQ    = (size_t)BATCH * HEADS * LFULL * HD;
    const size_t NC    = (size_t)BATCH * HEADS * CMAX * HD;
    const size_t NMD   = (size_t)MTOT * DDIM;
    const size_t PAD   = 8192;

    unsigned short* itemb  = (unsigned short*)alloc(NITEM * 2);
    unsigned short* Wqkvb  = (unsigned short*)alloc((size_t)NQKV * EDIM * 2);
    unsigned short* Wob    = (unsigned short*)alloc(NW * 2);
    unsigned short* W1b    = (unsigned short*)alloc(NW * 2);
    unsigned short* qb     = (unsigned short*)alloc(NQ * 2 + PAD);
    unsigned short* kcb    = (unsigned short*)alloc(NC * 2 + PAD);
    unsigned short* vcb    = (unsigned short*)alloc(NC * 2 + PAD);
    unsigned short* aob    = (unsigned short*)alloc(NMD * 2);
    float* fbuf  = (float*)alloc(NMD * 4);
    float* uball = (float*)alloc((size_t)BATCH * NQKV * 4);
    float* part  = (float*)alloc((size_t)MTOT * 8 * 4);
    int* cidx    = (int*)alloc((size_t)BATCH * 512 * 4);
    int* cnt     = (int*)alloc((size_t)BATCH * 32 * 4);

    cvt_kernel<<<dim3((NITEM / 4 + 255) / 256), 256, 0, stream>>>(item, itemb, NITEM / 4);
    packqkv_kernel<<<dim3(DDIM * EDIM / 4 / 256, 3), 256, 0, stream>>>(Wq, Wk, Wv, Wqkvb);
    Cvt2 c2;
    c2.s[0] = Wo; c2.s[1] = W1; c2.d[0] = Wob; c2.d[1] = W1b;
    cvt2_kernel<<<dim3(NW / 4 / 256, 2), 256, 0, stream>>>(c2, NW / 4);

    compact_kernel<<<dim3(BATCH), 64, 0, stream>>>(resp, cidx, cnt);

    user_bias_kernel<<<dim3(BATCH, 3), 256, 0, stream>>>(
        user, Wq, bq, Wk, bk, Wv, bv, uball, qb, kcb, vcb);

    gemm_qkv<<<dim3(NQKV / 128, MTOT / 128), 256, 0, stream>>>(
        itemb, Wqkvb, uball, cidx, qb, kcb, vcb);

    attn_mfma<<<dim3(SLATES, HEADS, BATCH), 256, 0, stream>>>(qb, kcb, vcb, cnt, aob);

    dim3 gg(DDIM / 128, MTOT / 128);
    gemm_bf16<1><<<gg, 256, 0, stream>>>(aob, Wob, bo, fbuf, nullptr, nullptr);
    ln_kernel<<<dim3(MTOT / 4), 256, 0, stream>>>(fbuf, lng, lnb, aob);
    gemm_bf16<2><<<gg, 256, 0, stream>>>(aob, W1b, b1, nullptr, W2, part);
    w2red_kernel<<<dim3((MTOT + 255) / 256), 256, 0, stream>>>(part, b2, out);
}